// Round 11
// baseline (257.770 us; speedup 1.0000x reference)
//
#include <hip/hip_runtime.h>

typedef short bf16x8 __attribute__((ext_vector_type(8)));
typedef float f32x4 __attribute__((ext_vector_type(4)));

// Problem constants (fixed by reference setup_inputs)
constexpr int Bc = 4;
constexpr int Nc = 50000;
constexpr int Kc = 10;
constexpr int Fc = 128;
constexpr int Hc = 16;
constexpr int Cc = 64;            // 4*H output channels
constexpr int NODES = Bc * Nc;    // 200000
constexpr int NPB = 8;            // nodes per tile
constexpr int ROWS = NPB * Kc;    // 80 GEMM rows per tile
constexpr int MT = ROWS / 16;     // 5 M-tiles
constexpr int BLK = 256;          // 4 waves, N-split (wave w owns cols 16w..16w+15)
constexpr int NTILES = NODES / NPB;  // 25000
constexpr int GRID = 1024;           // persistent, 4 blocks/CU

// LDS: single x buffer fp32 [80 rows][512 B], 16B-unit XOR-swizzled via SOURCE
// addr = 40960 B -> 4 blocks/CU (163840 = full LDS).
// Epilogue aliasing: hw f32 [80][64] (un-padded, 20480 B) at bytes [20480,40960);
// front half [0,20480) receives the NEXT tile's j0..j4 DMA during the epilogue;
// back half receives j5..j9 after the store barrier. ol [8][68] overwrites hw
// (post-barrier) at [20480, 22656).
constexpr int BUF_BYTES = ROWS * Fc * 4;   // 40960
constexpr int HW_OFF = 20480;

__device__ __forceinline__ unsigned short f2bf(float f) {
    // round-to-nearest-even fp32 -> bf16 (prep kernel only)
    unsigned u = __builtin_bit_cast(unsigned, f);
    return (unsigned short)((u + 0x7fffu + ((u >> 16) & 1u)) >> 16);
}

__device__ __forceinline__ unsigned cvtpk(float lo, float hi) {
    // packed RNE fp32->bf16: D[15:0]=bf16(lo), D[31:16]=bf16(hi)
    unsigned r;
    asm("v_cvt_pk_bf16_f32 %0, %1, %2" : "=v"(r) : "v"(lo), "v"(hi));
    return r;
}

// raw barrier: order LDS only; NEVER drains vmcnt -> DMA stays in flight.
__device__ __forceinline__ void barrier_lds() {
    asm volatile("s_waitcnt lgkmcnt(0)" ::: "memory");
    __builtin_amdgcn_sched_barrier(0);
    __builtin_amdgcn_s_barrier();
    __builtin_amdgcn_sched_barrier(0);
}

// Prep: W [128][64] f32 -> per-lane B-fragment image in d_ws (bf16).
// dst = n*2048 + l*32 + kc*8 + j  <->  c = n*16 + (l&15), f = kc*32 + (l>>4)*8 + j.
__global__ __launch_bounds__(256)
void prep_w(const float* __restrict__ W, unsigned short* __restrict__ wt) {
    const int dst = blockIdx.x * 256 + threadIdx.x;   // 8192 total
    const int j  = dst & 7;
    const int kc = (dst >> 3) & 3;
    const int l  = (dst >> 5) & 63;
    const int n  = dst >> 11;
    const int c  = n * 16 + (l & 15);
    const int f  = kc * 32 + (l >> 4) * 8 + j;
    wt[dst] = f2bf(W[f * 64 + c]);
}

__global__ __launch_bounds__(BLK, 4)
void gat_kernel(const float* __restrict__ x,
                const unsigned short* __restrict__ wt_ws,
                const float* __restrict__ a,
                float* __restrict__ out)
{
    __shared__ __align__(16) char smem[BUF_BYTES];

    const int t   = threadIdx.x;
    const int w   = t >> 6;    // wave -> col-tile (N-split, as R8)
    const int l   = t & 63;
    const int lr  = l & 15;    // A-row / B-col within 16-tile
    const int lk  = l >> 4;    // k sub-block (8 contiguous k)
    const int l5  = l >> 5;
    const int l31 = l & 31;
    const int h   = t & 15;

    // B fragments (own col-tile only), then drain so vmcnt counts only DMA
    bf16x8 bfrag[4];
    {
        const bf16x8* wp = reinterpret_cast<const bf16x8*>(wt_ws + w * 2048 + l * 32);
#pragma unroll
        for (int kc = 0; kc < 4; ++kc) bfrag[kc] = wp[kc];
    }
    const float ar0 = a[h];
    const float ar1 = a[16 + h];
    const float ar2 = a[32 + h];
    const float ar3 = a[48 + h];
    asm volatile("s_waitcnt vmcnt(0)" ::: "memory");
    __builtin_amdgcn_sched_barrier(0);

    // DMA geometry (identical to R8): instr j, wave w, lane l covers
    // row j*8 + w*2 + l5, 16B source unit (l&31)^(row&7); LDS dest linear
    // (uniform base j*4096 + w*1024, +lane*16) => slot u of row r holds global
    // unit u^(r&7); reads XOR the same way.
    const int rsub = w * 2 + l5;                 // == row & 7 for every j
    const int unit = l31 ^ rsub;
    const size_t lane_goff = (size_t)rsub * 512 + (size_t)unit * 16;

    auto issue = [&](int tl, int j0, int j1) {
        const char* gsrc = reinterpret_cast<const char*>(x) + (size_t)tl * BUF_BYTES + lane_goff;
        for (int j = j0; j < j1; ++j)
            __builtin_amdgcn_global_load_lds(
                (const __attribute__((address_space(1))) void*)(gsrc + j * 4096),
                (__attribute__((address_space(3))) void*)(smem + j * 4096 + w * 1024),
                16, 0, 0);
    };

    int tile = blockIdx.x;
    issue(tile, 0, 5);   // early half: rows 0..39  -> bytes [0, 20480)
    issue(tile, 5, 10);  // late half:  rows 40..79 -> bytes [20480, 40960)

    const int rsw = lr & 7;
    for (;;) {
        const int ntile = tile + GRID;

        // ---- compute part 1: m0,m1 (rows 0..31) once early-half landed ----
        asm volatile("s_waitcnt vmcnt(5)" ::: "memory");
        __builtin_amdgcn_sched_barrier(0);
        __builtin_amdgcn_s_barrier();
        __builtin_amdgcn_sched_barrier(0);

        f32x4 acc[MT];
#pragma unroll
        for (int m = 0; m < MT; ++m) acc[m] = (f32x4){0.f, 0.f, 0.f, 0.f};

#pragma unroll
        for (int m = 0; m < 2; ++m) {
            const char* xrow = smem + (m * 16 + lr) * 512;
#pragma unroll
            for (int kc = 0; kc < 4; ++kc) {
                const int u0 = kc * 8 + lk * 2;
                const f32x4 p0 = *reinterpret_cast<const f32x4*>(xrow + ((u0)     ^ rsw) * 16);
                const f32x4 p1 = *reinterpret_cast<const f32x4*>(xrow + ((u0 + 1) ^ rsw) * 16);
                union { unsigned u[4]; bf16x8 v; } af;
                af.u[0] = cvtpk(p0[0], p0[1]);
                af.u[1] = cvtpk(p0[2], p0[3]);
                af.u[2] = cvtpk(p1[0], p1[1]);
                af.u[3] = cvtpk(p1[2], p1[3]);
                acc[m] = __builtin_amdgcn_mfma_f32_16x16x32_bf16(af.v, bfrag[kc], acc[m], 0, 0, 0);
            }
        }

        // ---- compute part 2: m2..m4 (rows 32..79) once late-half landed ----
        asm volatile("s_waitcnt vmcnt(0)" ::: "memory");
        __builtin_amdgcn_sched_barrier(0);
        __builtin_amdgcn_s_barrier();
        __builtin_amdgcn_sched_barrier(0);

#pragma unroll
        for (int m = 2; m < MT; ++m) {
            const char* xrow = smem + (m * 16 + lr) * 512;
#pragma unroll
            for (int kc = 0; kc < 4; ++kc) {
                const int u0 = kc * 8 + lk * 2;
                const f32x4 p0 = *reinterpret_cast<const f32x4*>(xrow + ((u0)     ^ rsw) * 16);
                const f32x4 p1 = *reinterpret_cast<const f32x4*>(xrow + ((u0 + 1) ^ rsw) * 16);
                union { unsigned u[4]; bf16x8 v; } af;
                af.u[0] = cvtpk(p0[0], p0[1]);
                af.u[1] = cvtpk(p0[2], p0[3]);
                af.u[2] = cvtpk(p1[0], p1[1]);
                af.u[3] = cvtpk(p1[2], p1[3]);
                acc[m] = __builtin_amdgcn_mfma_f32_16x16x32_bf16(af.v, bfrag[kc], acc[m], 0, 0, 0);
            }
        }

        // ---- x fully consumed ----
        barrier_lds();

        // ---- overlap: issue next tile's EARLY half into the freed front half ----
        if (ntile < NTILES) issue(ntile, 0, 5);

        // ---- acc -> hw f32 [80][64] at back half (D-frag: row=lk*4+r, col=w*16+lr) ----
        {
            float* hw = reinterpret_cast<float*>(smem + HW_OFF);
            const int col = w * 16 + lr;
#pragma unroll
            for (int m = 0; m < MT; ++m) {
                const int rbase = m * 16 + lk * 4;
#pragma unroll
                for (int r = 0; r < 4; ++r)
                    hw[(rbase + r) * 64 + col] = acc[m][r];
            }
        }
        barrier_lds();

        // ---- online softmax over K=10 + leaky relu, thread = (node, head) ----
        float o0, o1, o2, o3;
        if (t < NPB * Hc) {   // 128 active
            const int ln = t >> 4;
            const float* hwb = reinterpret_cast<const float*>(smem + HW_OFF) + (ln * Kc) * 64 + h * 4;
            float mx = -1e30f, lsum = 0.f;
            o0 = 0.f; o1 = 0.f; o2 = 0.f; o3 = 0.f;
#pragma unroll
            for (int k = 0; k < Kc; ++k) {
                const float4 hv = *reinterpret_cast<const float4*>(hwb + k * 64);
                const float lg = fmaf(hv.x, ar0, fmaf(hv.y, ar1, fmaf(hv.z, ar2, hv.w * ar3)));
                const float mn = fmaxf(mx, lg);
                const float s  = __expf(mx - mn);
                const float p  = __expf(lg - mn);
                mx = mn;
                lsum = fmaf(lsum, s, p);
                o0 = fmaf(o0, s, p * hv.x);
                o1 = fmaf(o1, s, p * hv.y);
                o2 = fmaf(o2, s, p * hv.z);
                o3 = fmaf(o3, s, p * hv.w);
            }
            const float inv = 1.f / lsum;
            o0 *= inv; o1 *= inv; o2 *= inv; o3 *= inv;
            o0 = fmaxf(o0, 0.2f * o0);   // leaky_relu slope 0.2
            o1 = fmaxf(o1, 0.2f * o1);
            o2 = fmaxf(o2, 0.2f * o2);
            o3 = fmaxf(o3, 0.2f * o3);
        }
        barrier_lds();   // all hw reads done -> ol may overwrite hw

        if (t < NPB * Hc) {
            float* ol = reinterpret_cast<float*>(smem + HW_OFF);
            *reinterpret_cast<float4*>(ol + (t >> 4) * 68 + h * 4) = make_float4(o0, o1, o2, o3);
        }
        barrier_lds();

        // ---- store transposed [B, 64, N], coalesced float4 ----
        if (t < 128) {
            const float* ol = reinterpret_cast<const float*>(smem + HW_OFF);
            const int c  = t >> 1;   // channel 0..63
            const int nq = t & 1;    // node quad 0..1
            const int nb = tile * NPB;
            const int b  = nb / Nc;
            const int n0 = nb - b * Nc;
            float4 v;
            v.x = ol[(nq * 4 + 0) * 68 + c];
            v.y = ol[(nq * 4 + 1) * 68 + c];
            v.z = ol[(nq * 4 + 2) * 68 + c];
            v.w = ol[(nq * 4 + 3) * 68 + c];
            *reinterpret_cast<float4*>(out + ((size_t)b * Cc + c) * Nc + n0 + nq * 4) = v;
        }
        barrier_lds();   // ol reads done -> late half may overwrite

        // ---- issue next tile's LATE half into the back half ----
        if (ntile < NTILES) issue(ntile, 5, 10);

        tile = ntile;
        if (tile >= NTILES) break;
    }
}

extern "C" void kernel_launch(void* const* d_in, const int* in_sizes, int n_in,
                              void* d_out, int out_size, void* d_ws, size_t ws_size,
                              hipStream_t stream) {
    const float* x = (const float*)d_in[0];
    const float* W = (const float*)d_in[1];
    const float* a = (const float*)d_in[2];
    float* out = (float*)d_out;
    unsigned short* wt = (unsigned short*)d_ws;   // 16 KB used

    prep_w<<<32, 256, 0, stream>>>(W, wt);
    gat_kernel<<<GRID, BLK, 0, stream>>>(x, wt, a, out);
}